// Round 17
// baseline (1305.707 us; speedup 1.0000x reference)
//
#include <hip/hip_runtime.h>
#include <hip/hip_bf16.h>
#include <math.h>

// ---------------------------------------------------------------------------
// TransformerBlock fwd: ln1 -> qkv gemm -> causal flash attn -> proj+res
//   -> ln2 -> ffn1(buggy-gelu) -> ffn2+res.  bf16 MFMA, fp32 softmax/LN.
// R17: qkv -> gemm3q: 256x128 BK=32, dbuf=2 (48KB LDS) => 3 blocks/CU, so
//   768 blocks = ONE round (kills the 1.5-round tail that cost ~40us).
//   ffn1 stays gemm3b (2 clean rounds @ 2/CU); proj/ffn2 gemm2c; rest R16.
// ---------------------------------------------------------------------------

typedef short bf16x8 __attribute__((ext_vector_type(8)));
typedef float f32x4 __attribute__((ext_vector_type(4)));
typedef short short4v __attribute__((ext_vector_type(4)));

#define MFMA16x32(a, b, c) __builtin_amdgcn_mfma_f32_16x16x32_bf16((a), (b), (c), 0, 0, 0)

__device__ __forceinline__ short f2bs(float f) {
    unsigned u = __builtin_bit_cast(unsigned, f);
    unsigned r = (u + 0x7FFFu + ((u >> 16) & 1u)) >> 16;
    return (short)(unsigned short)r;
}

__device__ __forceinline__ float bs2f(short s) {
    unsigned u = ((unsigned)(unsigned short)s) << 16;
    return __builtin_bit_cast(float, u);
}

__device__ __forceinline__ void gload_lds16(const void* g, void* l) {
    __builtin_amdgcn_global_load_lds(
        (const __attribute__((address_space(1))) unsigned int*)g,
        (__attribute__((address_space(3))) unsigned int*)l, 16, 0, 0);
}

template <int N>
__device__ __forceinline__ void vmw() {
    if constexpr (N == 0) asm volatile("s_waitcnt vmcnt(0)" ::: "memory");
    else if constexpr (N == 3) asm volatile("s_waitcnt vmcnt(3)" ::: "memory");
    else if constexpr (N == 6) asm volatile("s_waitcnt vmcnt(6)" ::: "memory");
    else if constexpr (N == 8) asm volatile("s_waitcnt vmcnt(8)" ::: "memory");
}

// ---------- fused weight transposes, 64x64 tiles: fp32 (RxC) -> bf16 (CxR) --
__global__ __launch_bounds__(256) void transpose_all_kernel(
    const float* __restrict__ wq, const float* __restrict__ wk,
    const float* __restrict__ wv, const float* __restrict__ wo,
    const float* __restrict__ w1, const float* __restrict__ w2,
    short* __restrict__ wqkvT, short* __restrict__ woT,
    short* __restrict__ w1T, short* __restrict__ w2T) {
    const int D = 2048;
    __shared__ float tile[64][65];
    int blk = blockIdx.x;
    const float* in;
    short* out;
    int R, C, bx, by;
    if (blk < 4096) {
        int r = blk >> 10;
        in = (r == 0) ? wq : (r == 1) ? wk : (r == 2) ? wv : wo;
        out = (r < 3) ? (wqkvT + (size_t)r * D * D) : woT;
        R = D; C = D;
        int lb = blk & 1023; bx = lb & 31; by = lb >> 5;
    } else if (blk < 8192) {
        in = w1; out = w1T; R = D; C = 4 * D;
        int lb = blk - 4096; bx = lb & 127; by = lb >> 7;
    } else {
        in = w2; out = w2T; R = 4 * D; C = D;
        int lb = blk - 8192; bx = lb & 31; by = lb >> 5;
    }
    const int tx = threadIdx.x & 31;
    const int ty = threadIdx.x >> 5;
    const int c0 = bx * 64, r0 = by * 64;
#pragma unroll
    for (int i = 0; i < 8; ++i) {
        int r = ty + i * 8;
        float2 v = *(const float2*)(in + (size_t)(r0 + r) * C + c0 + tx * 2);
        tile[r][tx * 2] = v.x;
        tile[r][tx * 2 + 1] = v.y;
    }
    __syncthreads();
#pragma unroll
    for (int i = 0; i < 8; ++i) {
        int c = ty + i * 8;
        short2 o;
        o.x = f2bs(tile[tx * 2][c]);
        o.y = f2bs(tile[tx * 2 + 1][c]);
        *(short2*)(out + (size_t)(c0 + c) * R + r0 + tx * 2) = o;
    }
}

// ---------- layernorm fp32 row -> bf16 row, plus bf16 copy of x ----------
__global__ __launch_bounds__(256) void ln_kernel(const float* __restrict__ x,
                                                 const float* __restrict__ sc,
                                                 const float* __restrict__ sh,
                                                 short* __restrict__ out,
                                                 short* __restrict__ xb) {
    const int D = 2048;
    const int row = blockIdx.x;
    const int tid = threadIdx.x;
    __shared__ float red[4];
    const float4* xr = (const float4*)(x + (size_t)row * D);
    float4 v0 = xr[tid];
    float4 v1 = xr[tid + 256];
    float vals0[4] = {v0.x, v0.y, v0.z, v0.w};
    float vals1[4] = {v1.x, v1.y, v1.z, v1.w};

    float s = vals0[0] + vals0[1] + vals0[2] + vals0[3] + vals1[0] + vals1[1] + vals1[2] + vals1[3];
#pragma unroll
    for (int off = 32; off; off >>= 1) s += __shfl_xor(s, off);
    if ((tid & 63) == 0) red[tid >> 6] = s;
    __syncthreads();
    float mean = (red[0] + red[1] + red[2] + red[3]) * (1.0f / 2048.0f);
    __syncthreads();

    float q = 0.0f;
#pragma unroll
    for (int j = 0; j < 4; ++j) {
        float t0 = vals0[j] - mean;
        float t1 = vals1[j] - mean;
        q += t0 * t0 + t1 * t1;
    }
#pragma unroll
    for (int off = 32; off; off >>= 1) q += __shfl_xor(q, off);
    if ((tid & 63) == 0) red[tid >> 6] = q;
    __syncthreads();
    float var = (red[0] + red[1] + red[2] + red[3]) * (1.0f / 2048.0f);
    float inv = rsqrtf(var + 1e-5f);

    const int c0 = tid * 4;
    const int c1 = (tid + 256) * 4;
    short4v o0, o1, b0, b1;
#pragma unroll
    for (int j = 0; j < 4; ++j) {
        o0[j] = f2bs(sc[c0 + j] * ((vals0[j] - mean) * inv) + sh[c0 + j]);
        o1[j] = f2bs(sc[c1 + j] * ((vals1[j] - mean) * inv) + sh[c1 + j]);
        b0[j] = f2bs(vals0[j]);
        b1[j] = f2bs(vals1[j]);
    }
    *(short4v*)(out + (size_t)row * D + c0) = o0;
    *(short4v*)(out + (size_t)row * D + c1) = o1;
    *(short4v*)(xb + (size_t)row * D + c0) = b0;
    *(short4v*)(xb + (size_t)row * D + c1) = b1;
}

// ---------- layernorm bf16 row (D=2048) -> bf16 row ----------
__global__ __launch_bounds__(256) void ln_bf16_kernel(const short* __restrict__ x,
                                                      const float* __restrict__ sc,
                                                      const float* __restrict__ sh,
                                                      short* __restrict__ out) {
    const int D = 2048;
    const int row = blockIdx.x;
    const int tid = threadIdx.x;
    __shared__ float red[4];
    bf16x8 v = *(const bf16x8*)(x + (size_t)row * D + tid * 8);
    float vals[8];
#pragma unroll
    for (int j = 0; j < 8; ++j) vals[j] = bs2f(v[j]);

    float s = 0.f;
#pragma unroll
    for (int j = 0; j < 8; ++j) s += vals[j];
#pragma unroll
    for (int off = 32; off; off >>= 1) s += __shfl_xor(s, off);
    if ((tid & 63) == 0) red[tid >> 6] = s;
    __syncthreads();
    float mean = (red[0] + red[1] + red[2] + red[3]) * (1.0f / 2048.0f);
    __syncthreads();

    float q = 0.0f;
#pragma unroll
    for (int j = 0; j < 8; ++j) {
        float t = vals[j] - mean;
        q += t * t;
    }
#pragma unroll
    for (int off = 32; off; off >>= 1) q += __shfl_xor(q, off);
    if ((tid & 63) == 0) red[tid >> 6] = q;
    __syncthreads();
    float var = (red[0] + red[1] + red[2] + red[3]) * (1.0f / 2048.0f);
    float inv = rsqrtf(var + 1e-5f);

    const int c0 = tid * 8;
    bf16x8 o;
#pragma unroll
    for (int j = 0; j < 8; ++j)
        o[j] = f2bs(sc[c0 + j] * ((vals[j] - mean) * inv) + sh[c0 + j]);
    *(bf16x8*)(out + (size_t)row * D + c0) = o;
}

// ---------- gemm3q: 256x128, BK=32, dbuf=2 (48KB) -> 3 blocks/CU (qkv) -----
// 128B super-rows, 3-bit slot XOR (conflict-free). EPI 0: bf16 out.
__global__ __launch_bounds__(512, 6) void gemm3q(const short* __restrict__ A,
                                                 const short* __restrict__ Bt,
                                                 int M, int N, int K,
                                                 short* __restrict__ Cout) {
    extern __shared__ __align__(16) short lds[];  // 2 * 12288 shorts = 48KB
    const int tid = threadIdx.x;
    const int lane = tid & 63;
    const int wid = tid >> 6;
    const int wm = wid >> 1, wn = wid & 1;
    const int l15 = lane & 15, grp = lane >> 4;

    const int gx = gridDim.x;
    int flat = (int)blockIdx.y * gx + (int)blockIdx.x;
    const int cpx = (gx * (int)gridDim.y) >> 3;
    flat = (flat & 7) * cpx + (flat >> 3);
    const int bx = flat % gx, by = flat / gx;
    const long m0 = (long)by * 256, n0 = (long)bx * 128;

    f32x4 zero = {0.f, 0.f, 0.f, 0.f};
    f32x4 acc[4][4];
#pragma unroll
    for (int i = 0; i < 4; i++)
#pragma unroll
        for (int j = 0; j < 4; j++) acc[i][j] = zero;

    auto STAGE = [&](int t, int b) {
        short* bufA = lds + b * 12288;
        short* bufB = bufA + 8192;
        const long k0 = (long)t << 5;
#pragma unroll
        for (int j = 0; j < 2; ++j) {
            int c = tid + j * 512;
            int sr = c >> 3, ps = c & 7;
            int ls = ps ^ (sr & 7);
            int row = sr * 2 + (ls >> 2), kc = ls & 3;
            gload_lds16(A + (size_t)(m0 + row) * K + k0 + kc * 8, bufA + (size_t)c * 8);
        }
        {
            int c = tid;
            int sr = c >> 3, ps = c & 7;
            int ls = ps ^ (sr & 7);
            int row = sr * 2 + (ls >> 2), kc = ls & 3;
            gload_lds16(Bt + (size_t)(n0 + row) * K + k0 + kc * 8, bufB + (size_t)c * 8);
        }
    };

    const int nt = K >> 5;
    STAGE(0, 0);
    STAGE(1, 1);

    for (int t = 0; t < nt; ++t) {
        if (t + 1 < nt) { vmw<3>(); } else { vmw<0>(); }
        __builtin_amdgcn_s_barrier();
        __builtin_amdgcn_sched_barrier(0);

        const short* bufA = lds + (t & 1) * 12288;
        const short* bufB = bufA + 8192;
        bf16x8 af[4], bfr[4];
#pragma unroll
        for (int m = 0; m < 4; ++m) {
            int row = wm * 64 + m * 16 + l15;
            int sr = row >> 1;
            int ps = ((row & 1) * 4 + grp) ^ (sr & 7);
            af[m] = *(const bf16x8*)(bufA + sr * 64 + ps * 8);
        }
#pragma unroll
        for (int n = 0; n < 4; ++n) {
            int row = wn * 64 + n * 16 + l15;
            int sr = row >> 1;
            int ps = ((row & 1) * 4 + grp) ^ (sr & 7);
            bfr[n] = *(const bf16x8*)(bufB + sr * 64 + ps * 8);
        }
        __builtin_amdgcn_s_setprio(1);
#pragma unroll
        for (int m = 0; m < 4; ++m)
#pragma unroll
            for (int n = 0; n < 4; ++n)
                acc[m][n] = MFMA16x32(af[m], bfr[n], acc[m][n]);
        __builtin_amdgcn_s_setprio(0);
        asm volatile("s_waitcnt lgkmcnt(0)" ::: "memory");
        __builtin_amdgcn_s_barrier();
        __builtin_amdgcn_sched_barrier(0);
        if (t + 2 < nt) STAGE(t + 2, t & 1);
    }

#pragma unroll
    for (int m = 0; m < 4; m++) {
        long gr = m0 + wm * 64 + m * 16 + grp * 4;
#pragma unroll
        for (int n = 0; n < 4; n++) {
            long gcol = n0 + wn * 64 + n * 16 + l15;
#pragma unroll
            for (int r = 0; r < 4; r++)
                Cout[(gr + r) * N + gcol] = f2bs(acc[m][n][r]);
        }
    }
}

// ---------- gemm3b: 256x128, BK=32, 3-deep, 72KB LDS -> 2 blocks/CU (ffn1) -
template <int EPI>
__global__ __launch_bounds__(512, 4) void gemm3b(const short* __restrict__ A,
                                                 const short* __restrict__ Bt,
                                                 int M, int N, int K,
                                                 void* __restrict__ Cout,
                                                 const float* __restrict__ bias,
                                                 const float* __restrict__ res,
                                                 float gconst) {
    extern __shared__ __align__(16) short lds[];  // 3 * 12288 shorts = 72KB
    const int tid = threadIdx.x;
    const int lane = tid & 63;
    const int wid = tid >> 6;
    const int wm = wid >> 1, wn = wid & 1;
    const int l15 = lane & 15, grp = lane >> 4;

    const int gx = gridDim.x;
    int flat = (int)blockIdx.y * gx + (int)blockIdx.x;
    const int cpx = (gx * (int)gridDim.y) >> 3;
    flat = (flat & 7) * cpx + (flat >> 3);
    const int bx = flat % gx, by = flat / gx;
    const long m0 = (long)by * 256, n0 = (long)bx * 128;

    f32x4 zero = {0.f, 0.f, 0.f, 0.f};
    f32x4 acc[4][4];
#pragma unroll
    for (int i = 0; i < 4; i++)
#pragma unroll
        for (int j = 0; j < 4; j++) acc[i][j] = zero;

    auto STAGE = [&](int t, int b) {
        short* bufA = lds + b * 12288;
        short* bufB = bufA + 8192;
        const long k0 = (long)t << 5;
#pragma unroll
        for (int j = 0; j < 2; ++j) {
            int c = tid + j * 512;
            int sr = c >> 3, ps = c & 7;
            int ls = ps ^ (sr & 7);
            int row = sr * 2 + (ls >> 2), kc = ls & 3;
            gload_lds16(A + (size_t)(m0 + row) * K + k0 + kc * 8, bufA + (size_t)c * 8);
        }
        {
            int c = tid;
            int sr = c >> 3, ps = c & 7;
            int ls = ps ^ (sr & 7);
            int row = sr * 2 + (ls >> 2), kc = ls & 3;
            gload_lds16(Bt + (size_t)(n0 + row) * K + k0 + kc * 8, bufB + (size_t)c * 8);
        }
    };

    const int nt = K >> 5;
    STAGE(0, 0);
    STAGE(1, 1);
    int cur = 0, nx2 = 2;

    for (int t = 0; t < nt; ++t) {
        if (t + 2 < nt) {
            STAGE(t + 2, nx2);
            vmw<6>();
        } else if (t + 1 < nt) {
            vmw<3>();
        } else {
            vmw<0>();
        }
        __builtin_amdgcn_s_barrier();
        __builtin_amdgcn_sched_barrier(0);

        const short* bufA = lds + cur * 12288;
        const short* bufB = bufA + 8192;
        bf16x8 af[4], bfr[4];
#pragma unroll
        for (int m = 0; m < 4; ++m) {
            int row = wm * 64 + m * 16 + l15;
            int sr = row >> 1;
            int ps = ((row & 1) * 4 + grp) ^ (sr & 7);
            af[m] = *(const bf16x8*)(bufA + sr * 64 + ps * 8);
        }
#pragma unroll
        for (int n = 0; n < 4; ++n) {
            int row = wn * 64 + n * 16 + l15;
            int sr = row >> 1;
            int ps = ((row & 1) * 4 + grp) ^ (sr & 7);
            bfr[n] = *(const bf16x8*)(bufB + sr * 64 + ps * 8);
        }
        __builtin_amdgcn_s_setprio(1);
#pragma unroll
        for (int m = 0; m < 4; ++m)
#pragma unroll
            for (int n = 0; n < 4; ++n)
                acc[m][n] = MFMA16x32(af[m], bfr[n], acc[m][n]);
        __builtin_amdgcn_s_setprio(0);
        asm volatile("s_waitcnt lgkmcnt(0)" ::: "memory");
        __builtin_amdgcn_s_barrier();
        __builtin_amdgcn_sched_barrier(0);
        cur = (cur == 2) ? 0 : cur + 1;
        nx2 = (nx2 == 2) ? 0 : nx2 + 1;
    }

#pragma unroll
    for (int m = 0; m < 4; m++) {
        long gr = m0 + wm * 64 + m * 16 + grp * 4;
#pragma unroll
        for (int n = 0; n < 4; n++) {
            long gcol = n0 + wn * 64 + n * 16 + l15;
#pragma unroll
            for (int r = 0; r < 4; r++) {
                float vv = acc[m][n][r];
                long idx = (gr + r) * N + gcol;
                if constexpr (EPI == 0) {
                    ((short*)Cout)[idx] = f2bs(vv);
                } else {
                    float t2 = vv + bias[gcol];
                    float g = 0.5f * t2 * (1.0f + gconst * (t2 + 0.044715f * t2 * t2 * t2));
                    ((short*)Cout)[idx] = f2bs(g);
                }
            }
        }
    }
}

// ---------- gemm2c: 128x128, BK=64, 256 thr, 2-deep dbuf, 64KB -> 2 blk/CU --
// EPI 4: f32=acc+bias+bf16res   5: bf16=acc+bias+bf16res
template <int EPI>
__global__ __launch_bounds__(256, 2) void gemm2c(const short* __restrict__ A,
                                                 const short* __restrict__ Bt,
                                                 int M, int N, int K,
                                                 void* __restrict__ Cout,
                                                 const float* __restrict__ bias,
                                                 const float* __restrict__ res,
                                                 float gconst) {
    extern __shared__ __align__(16) short lds[];  // 2 * 16384 shorts = 64KB
    const int tid = threadIdx.x;
    const int lane = tid & 63;
    const int wid = tid >> 6;
    const int wm = wid >> 1, wn = wid & 1;
    const int l15 = lane & 15, grp = lane >> 4;

    const int gx = gridDim.x;
    int flat = (int)blockIdx.y * gx + (int)blockIdx.x;
    const int cpx = (gx * (int)gridDim.y) >> 3;
    flat = (flat & 7) * cpx + (flat >> 3);
    const int bx = flat % gx, by = flat / gx;
    const long m0 = (long)by * 128, n0 = (long)bx * 128;

    f32x4 zero = {0.f, 0.f, 0.f, 0.f};
    f32x4 acc[4][4];
#pragma unroll
    for (int i = 0; i < 4; i++)
#pragma unroll
        for (int j = 0; j < 4; j++) acc[i][j] = zero;

    auto STAGE = [&](int t, int b) {
        short* bufA = lds + b * 16384;
        short* bufB = bufA + 8192;
        const long k0 = (long)t << 6;
#pragma unroll
        for (int j = 0; j < 4; ++j) {
            int c = tid + j * 256;
            int row = c >> 3, sl = (c & 7) ^ (row & 7);
            gload_lds16(A + (size_t)(m0 + row) * K + k0 + sl * 8, bufA + (size_t)c * 8);
        }
#pragma unroll
        for (int j = 0; j < 4; ++j) {
            int c = tid + j * 256;
            int row = c >> 3, sl = (c & 7) ^ (row & 7);
            gload_lds16(Bt + (size_t)(n0 + row) * K + k0 + sl * 8, bufB + (size_t)c * 8);
        }
    };

    const int nt = K >> 6;
    STAGE(0, 0);
    STAGE(1, 1);

    for (int t = 0; t < nt; ++t) {
        if (t + 1 < nt) { vmw<8>(); } else { vmw<0>(); }
        __builtin_amdgcn_s_barrier();
        __builtin_amdgcn_sched_barrier(0);

        const short* bufA = lds + (t & 1) * 16384;
        const short* bufB = bufA + 8192;
        bf16x8 af[2][4], bfr[2][4];
#pragma unroll
        for (int kk = 0; kk < 2; ++kk) {
#pragma unroll
            for (int m = 0; m < 4; ++m) {
                int row = wm * 64 + m * 16 + l15;
                af[kk][m] = *(const bf16x8*)(bufA + row * 64 + (((kk * 4 + grp) ^ (row & 7)) * 8));
            }
#pragma unroll
            for (int n = 0; n < 4; ++n) {
                int row = wn * 64 + n * 16 + l15;
                bfr[kk][n] = *(const bf16x8*)(bufB + row * 64 + (((kk * 4 + grp) ^ (row & 7)) * 8));
            }
        }
        __builtin_amdgcn_s_setprio(1);
#pragma unroll
        for (int kk = 0; kk < 2; ++kk)
#pragma unroll
            for (int m = 0; m < 4; ++m)
#pragma unroll
                for (int n = 0; n < 4; ++n)
                    acc[m][n] = MFMA16x32(af[kk][m], bfr[kk][n], acc[m][n]);
        __builtin_amdgcn_s_setprio(0);
        asm volatile("s_waitcnt lgkmcnt(0)" ::: "memory");
        __builtin_amdgcn_s_barrier();
        __builtin_amdgcn_sched_barrier(0);
        if (t + 2 < nt) STAGE(t + 2, t & 1);
    }

#pragma unroll
    for (int m = 0; m < 4; m++) {
        long gr = m0 + wm * 64 + m * 16 + grp * 4;
#pragma unroll
        for (int n = 0; n < 4; n++) {
            long gcol = n0 + wn * 64 + n * 16 + l15;
#pragma unroll
            for (int r = 0; r < 4; r++) {
                float vv = acc[m][n][r];
                long idx = (gr + r) * N + gcol;
                if constexpr (EPI == 5) {
                    ((short*)Cout)[idx] = f2bs(vv + bias[gcol] + bs2f(((const short*)res)[idx]));
                } else {  // EPI == 4
                    ((float*)Cout)[idx] = vv + bias[gcol] + bs2f(((const short*)res)[idx]);
                }
            }
        }
    }
}

// ---------- reshape: qkv V-cols -> Vt[32][128][2048] (transposed) ----------
__global__ __launch_bounds__(256) void reshape_v_kernel(const short* __restrict__ qkv,
                                                        short* __restrict__ Vt) {
    __shared__ short tile[32][33];
    const int bid = blockIdx.x;
    const int dt = bid & 3, st = (bid >> 2) & 63, bh = bid >> 8;
    const int b = bh >> 4, h = bh & 15;
    const int s0 = st * 32, d0 = dt * 32;
    const int tx = threadIdx.x & 31, ty = threadIdx.x >> 5;
#pragma unroll
    for (int i = 0; i < 4; ++i) {
        int s = ty + i * 8;
        tile[s][tx] = qkv[(size_t)(b * 2048 + s0 + s) * 6144 + 4096 + h * 128 + d0 + tx];
    }
    __syncthreads();
#pragma unroll
    for (int i = 0; i < 4; ++i) {
        int d = ty + i * 8;
        Vt[((size_t)bh * 128 + d0 + d) * 2048 + s0 + tx] = tile[tx][d];
    }
}

// ---------- causal flash attention, paired q-tiles + double-buffered K/V ----
__global__ __launch_bounds__(256) void flash3_kernel(const short* __restrict__ qp,  // qkv, ld 6144
                                                     const short* __restrict__ Vt,
                                                     short* __restrict__ ctx) {
    const int S = 2048, D = 2048, HD = 128, LD = 6144;
    __shared__ __align__(16) short Ks[2][64 * 128];
    __shared__ __align__(16) short Vs[2][64 * 128];
    __shared__ __align__(16) short Ps[4][16 * 64];
    const int tid = threadIdx.x;
    const int lane = tid & 63, wid = tid >> 6;
    const int l15 = lane & 15, grp = lane >> 4;

    int bid = (int)blockIdx.x;
    bid = (bid & 7) * 64 + (bid >> 3);
    const int p = bid & 15, bh = bid >> 4;
    const int b = bh >> 4, h = bh & 15;
    const int qtH = 31 - p;
    const int nH = qtH + 1;
    const float scale = 0.08838834764831845f;
    const float NEGINF = -__builtin_inff();

    const short* Kbase = qp + (size_t)b * S * LD + 2048 + (size_t)h * HD;
    const short* Vbase = Vt + (size_t)bh * 128 * S;
    short* Psw = &Ps[wid][0];

    f32x4 zero = {0.f, 0.f, 0.f, 0.f};
    bf16x8 aq[4];
    float m_[4], l_[4];
    f32x4 o[8];

    int qt = qtH;
    int qw = qt * 64 + wid * 16;
    {
        const short* qrow = qp + (size_t)(b * S + qw + l15) * LD + h * HD;
#pragma unroll
        for (int kc = 0; kc < 4; kc++) aq[kc] = *(const bf16x8*)(qrow + kc * 32 + grp * 8);
    }
#pragma unroll
    for (int r = 0; r < 4; r++) { m_[r] = NEGINF; l_[r] = 0.f; }
#pragma unroll
    for (int n = 0; n < 8; n++) o[n] = zero;

#pragma unroll
    for (int j = 0; j < 4; ++j) {
        int c = tid + j * 256;
        int r = c >> 4, sl = c & 15;
        gload_lds16(Kbase + (size_t)r * LD + ((sl ^ (r & 7)) * 8),
                    Ks[0] + (size_t)(wid * 64 + j * 256) * 8);
    }
#pragma unroll
    for (int j = 0; j < 4; ++j) {
        int c = tid + j * 256;
        int d = c >> 3, sl = c & 7;
        gload_lds16(Vbase + (size_t)d * S + ((sl ^ (d & 7)) * 8),
                    Vs[0] + (size_t)(wid * 64 + j * 256) * 8);
    }
    __syncthreads();

    int cur = 0;
    for (int i = 0; i < 33; ++i) {
        const int kt = (i < nH) ? i : (i - nH);
        const bool lastT = (kt == qt);

        if (i + 1 < 33) {
            const int ktn = (i + 1 < nH) ? (i + 1) : (i + 1 - nH);
            const long kn0 = (long)ktn * 64;
            const short* Kg = Kbase + (size_t)kn0 * LD;
            const short* Vg = Vbase + kn0;
            short* kd = Ks[cur ^ 1];
            short* vd = Vs[cur ^ 1];
#pragma unroll
            for (int j = 0; j < 4; ++j) {
                int c = tid + j * 256;
                int r = c >> 4, sl = c & 15;
                gload_lds16(Kg + (size_t)r * LD + ((sl ^ (r & 7)) * 8),
                            kd + (size_t)(wid * 64 + j * 256) * 8);
            }
#pragma unroll
            for (int j = 0; j < 4; ++j) {
                int c = tid + j * 256;
                int d = c >> 3, sl = c & 7;
                gload_lds16(Vg + (size_t)d * S + ((sl ^ (d & 7)) * 8),
                            vd + (size_t)(wid * 64 + j * 256) * 8);
            }
        }

        const short* Kc = Ks[cur];
        const short* Vc = Vs[cur];

        f32x4 s[4] = {zero, zero, zero, zero};
        __builtin_amdgcn_s_setprio(1);
#pragma unroll
        for (int n = 0; n < 4; ++n) {
            int r = n * 16 + l15;
#pragma unroll
            for (int kc = 0; kc < 4; ++kc) {
                bf16x8 kb = *(const bf16x8*)(Kc + r * 128 + (((kc * 4 + grp) ^ (r & 7)) * 8));
                s[n] = MFMA16x32(aq[kc], kb, s[n]);
            }
        }
        __builtin_amdgcn_s_setprio(0);

        float al[4];
#pragma unroll
        for (int r = 0; r < 4; ++r) {
            float v[4];
#pragma unroll
            for (int n = 0; n < 4; ++n) v[n] = s[n][r] * scale;
            if (lastT) {
                int qrel = wid * 16 + grp * 4 + r;
#pragma unroll
                for (int n = 0; n < 4; ++n)
                    if (n * 16 + l15 > qrel) v[n] = NEGINF;
            }
            float mx = fmaxf(fmaxf(v[0], v[1]), fmaxf(v[2], v[3]));
            mx = fmaxf(mx, __shfl_xor(mx, 1));
            mx = fmaxf(mx, __shfl_xor(mx, 2));
            mx = fmaxf(mx, __shfl_xor(mx, 4));
            mx = fmaxf(mx, __shfl_xor(mx, 8));
            float mn = fmaxf(m_[r], mx);
            float sc_ = __expf(m_[r] - mn);
            float rs = 0.f;
            int q = grp * 4 + r;
#pragma unroll
            for (int n = 0; n < 4; ++n) {
                v[n] = __expf(v[n] - mn);
                rs += v[n];
                Psw[q * 64 + (((n * 2 + (l15 >> 3)) ^ (q & 7)) * 8) + (l15 & 7)] = f2bs(v[n]);
            }
            rs += __shfl_xor(rs, 1);
            rs += __shfl_xor(rs, 2);
            rs += __shfl_xor(rs, 4);
            rs += __shfl_xor(rs, 8);
            l_[r] = l_[r] * sc_ + rs;
            m_[r] = mn;
            al[r] = sc_;
        }
#pragma unroll
        for (int n = 0; n < 8; n++) {
            f32x4 t = o[n];
            t[0] *= al[0]; t[1] *= al[1]; t[2] *= al[2]; t[3] *= al[3];
            o[n] = t;
        }

        bf16x8 pa[2];
#pragma unroll
        for (int kc = 0; kc < 2; ++kc)
            pa[kc] = *(const bf16x8*)(Psw + l15 * 64 + (((kc * 4 + grp) ^ (l15 & 7)) * 8));
        __builtin_amdgcn_s_setprio(1);
#pragma unroll
        for (int n = 0; n < 8; ++n) {
            int d = n * 16 + l15;
#pragma unroll
            for (int kc = 0; kc < 2; ++kc) {
                bf16x8 vb = *(const bf16x8*)(Vc + d * 64 + (((kc * 4 + grp) ^ (d & 7)) * 8));
                o[n] = MFMA16x32(pa[kc], vb, o[n]);
            }
        }
        __builtin_amdgcn_s_setprio(0);

        if (lastT) {
            float inv[4];
#pragma unroll
            for (int r = 0; r < 4; ++r) inv[r] = 1.0f / l_[r];
            short* cb_ = ctx + (size_t)(b * S + qw + grp * 4) * D + h * HD + l15;
#pragma unroll
            for (int n = 0; n < 8; ++n)
#pragma unroll
                for (int r = 0; r < 4; ++r)
                    cb_[(size_t)r * D + n * 16] = f2bs(o[n][r] * inv[r]);
            if (i < 32) {
                qt = 31 - qtH;
                qw = qt * 64 + wid * 16;
                const short* qrow = qp + (size_t)(b * S + qw + l15) * LD + h * HD;
#pragma unroll
                for (int kc = 0; kc < 4; kc++) aq[kc] = *(const bf16x8*)(qrow + kc * 32 + grp * 8);
#pragma unroll
                for (int r = 0; r < 4; r++) { m_[r] = NEGINF; l_[r] = 0.f; }
#pragma unroll
                for (int n = 0; n < 8; n++) o[n] = zero;
            }
        }
        __syncthreads();
        cur ^= 1;
    }
}

// ---------------------------------------------------------------------------
extern "C" void kernel_launch(void* const* d_in, const int* in_sizes, int n_in,
                              void* d_out, int out_size, void* d_ws, size_t ws_size,
                              hipStream_t stream) {
    const float* x    = (const float*)d_in[0];
    const float* wq   = (const float*)d_in[1];
    const float* wk   = (const float*)d_in[2];
    const float* wv   = (const float*)d_in[3];
    const float* wo   = (const float*)d_in[4];
    const float* bo   = (const float*)d_in[5];
    const float* w1   = (const float*)d_in[6];
    const float* b1   = (const float*)d_in[7];
    const float* w2   = (const float*)d_in[8];
    const float* b2   = (const float*)d_in[9];
    const float* lnsc = (const float*)d_in[10];
    const float* lnsh = (const float*)d_in[11];

    const int B = 2, S = 2048, D = 2048;
    const int M = B * S;  // 4096
    const int LDS_3Q = 2 * 12288 * 2;   // 49152 (gemm3q, 3 blk/CU)
    const int LDS_3B = 3 * 12288 * 2;   // 73728 (gemm3b)
    const int LDS_2C = 2 * 16384 * 2;   // 65536 (gemm2c)

    char* p = (char*)d_ws;
    short* wqkvT = (short*)p; p += (size_t)3 * D * D * 2;
    short* woT   = (short*)p; p += (size_t)D * D * 2;
    short* w1T   = (short*)p; p += (size_t)4 * D * D * 2;
    short* w2T   = (short*)p; p += (size_t)4 * D * D * 2;
    short* lnb   = (short*)p; p += (size_t)M * D * 2;
    short* qkvb  = (short*)p;
    short* h1    = qkvb;                                    // reuse qkv+ctx span
    p += (size_t)M * 3 * D * 2;
    short* ctxb  = (short*)p; p += (size_t)M * D * 2;
    short* x2    = (short*)p; p += (size_t)M * D * 2;       // bf16 residual (attn out)
    short* xb16  = (short*)p; p += (size_t)M * D * 2;       // bf16 copy of x

    short* Vt = x2;             // overlays x2 (proj writes x2 only after flash)

    const float gconst = tanhf(sqrtf(2.0f / 3.14159265358979323846f));

    hipFuncSetAttribute((const void*)&gemm3q, hipFuncAttributeMaxDynamicSharedMemorySize, LDS_3Q);
    hipFuncSetAttribute((const void*)&gemm3b<2>, hipFuncAttributeMaxDynamicSharedMemorySize, LDS_3B);
    hipFuncSetAttribute((const void*)&gemm2c<5>, hipFuncAttributeMaxDynamicSharedMemorySize, LDS_2C);
    hipFuncSetAttribute((const void*)&gemm2c<4>, hipFuncAttributeMaxDynamicSharedMemorySize, LDS_2C);

    dim3 blk(256);
    transpose_all_kernel<<<dim3(12288), blk, 0, stream>>>(
        wq, wk, wv, wo, w1, w2, wqkvT, woT, w1T, w2T);

    ln_kernel<<<dim3(M), blk, 0, stream>>>(x, lnsc, lnsh, lnb, xb16);
    // qkv: gemm3q, 3 blocks/CU -> grid 48x16 = 768 blocks = ONE round
    gemm3q<<<dim3(3 * D / 128, M / 256), dim3(512), LDS_3Q, stream>>>(
        lnb, wqkvT, M, 3 * D, D, qkvb);

    reshape_v_kernel<<<dim3(8192), blk, 0, stream>>>(qkvb, Vt);

    flash3_kernel<<<dim3(512), blk, 0, stream>>>(qkvb, Vt, ctxb);

    // proj: gemm2c EPI5 (bf16 out = acc + bo + bf16 x) -> grid 16x32 = 512
    gemm2c<5><<<dim3(D / 128, M / 128), blk, LDS_2C, stream>>>(
        ctxb, woT, M, D, D, x2, bo, (const float*)xb16, 0.f);
    ln_bf16_kernel<<<dim3(M), blk, 0, stream>>>(x2, lnsc, lnsh, lnb);
    // ffn1: gemm3b -> grid 64x16 = 1024 blocks (2 clean rounds @ 2/CU)
    gemm3b<2><<<dim3(4 * D / 128, M / 256), dim3(512), LDS_3B, stream>>>(
        lnb, w1T, M, 4 * D, D, h1, b1, nullptr, gconst);
    // ffn2: gemm2c EPI4 (f32 out = acc + b2 + bf16 x2) -> grid 16x32 = 512
    gemm2c<4><<<dim3(D / 128, M / 128), blk, LDS_2C, stream>>>(
        h1, w2T, M, D, 4 * D, (float*)d_out, b2, (const float*)x2, 0.f);
}

// Round 18
// 591.104 us; speedup vs baseline: 2.2089x; 2.2089x over previous
//
#include <hip/hip_runtime.h>
#include <hip/hip_bf16.h>
#include <math.h>

// ---------------------------------------------------------------------------
// TransformerBlock fwd: ln1 -> qkv gemm -> causal flash attn -> proj+res
//   -> ln2 -> ffn1(buggy-gelu) -> ffn2+res.  bf16 MFMA, fp32 softmax/LN.
// R18 = revert to R16 (verified best, 595us). R17's gemm3q (3 blk/CU)
//   failed: launch_bounds(512,6) capped VGPR at 40 < 64-reg accumulator
//   -> scratch spill (FETCH 1.6GB). Occupancy must respect the register
//   file, not just LDS. Final state:
//   qkv/ffn1 = gemm3b (256x128 BK=32, super-row swizzle, 2 blk/CU, 0 confl)
//   proj/ffn2 = gemm2c (128x128 BK=64, single-round, 2 blk/CU)
//   flash = paired-q-tile dbuf (512 blocks), 64x64 fused transposes,
//   bf16 residual chain.
// ---------------------------------------------------------------------------

typedef short bf16x8 __attribute__((ext_vector_type(8)));
typedef float f32x4 __attribute__((ext_vector_type(4)));
typedef short short4v __attribute__((ext_vector_type(4)));

#define MFMA16x32(a, b, c) __builtin_amdgcn_mfma_f32_16x16x32_bf16((a), (b), (c), 0, 0, 0)

__device__ __forceinline__ short f2bs(float f) {
    unsigned u = __builtin_bit_cast(unsigned, f);
    unsigned r = (u + 0x7FFFu + ((u >> 16) & 1u)) >> 16;
    return (short)(unsigned short)r;
}

__device__ __forceinline__ float bs2f(short s) {
    unsigned u = ((unsigned)(unsigned short)s) << 16;
    return __builtin_bit_cast(float, u);
}

__device__ __forceinline__ void gload_lds16(const void* g, void* l) {
    __builtin_amdgcn_global_load_lds(
        (const __attribute__((address_space(1))) unsigned int*)g,
        (__attribute__((address_space(3))) unsigned int*)l, 16, 0, 0);
}

template <int N>
__device__ __forceinline__ void vmw() {
    if constexpr (N == 0) asm volatile("s_waitcnt vmcnt(0)" ::: "memory");
    else if constexpr (N == 3) asm volatile("s_waitcnt vmcnt(3)" ::: "memory");
    else if constexpr (N == 6) asm volatile("s_waitcnt vmcnt(6)" ::: "memory");
    else if constexpr (N == 8) asm volatile("s_waitcnt vmcnt(8)" ::: "memory");
}

// ---------- fused weight transposes, 64x64 tiles: fp32 (RxC) -> bf16 (CxR) --
__global__ __launch_bounds__(256) void transpose_all_kernel(
    const float* __restrict__ wq, const float* __restrict__ wk,
    const float* __restrict__ wv, const float* __restrict__ wo,
    const float* __restrict__ w1, const float* __restrict__ w2,
    short* __restrict__ wqkvT, short* __restrict__ woT,
    short* __restrict__ w1T, short* __restrict__ w2T) {
    const int D = 2048;
    __shared__ float tile[64][65];
    int blk = blockIdx.x;
    const float* in;
    short* out;
    int R, C, bx, by;
    if (blk < 4096) {                      // wq/wk/wv/wo: 4 x 1024 blocks
        int r = blk >> 10;
        in = (r == 0) ? wq : (r == 1) ? wk : (r == 2) ? wv : wo;
        out = (r < 3) ? (wqkvT + (size_t)r * D * D) : woT;
        R = D; C = D;
        int lb = blk & 1023; bx = lb & 31; by = lb >> 5;
    } else if (blk < 8192) {               // w1 [2048][8192]
        in = w1; out = w1T; R = D; C = 4 * D;
        int lb = blk - 4096; bx = lb & 127; by = lb >> 7;
    } else {                               // w2 [8192][2048]
        in = w2; out = w2T; R = 4 * D; C = D;
        int lb = blk - 8192; bx = lb & 31; by = lb >> 5;
    }
    const int tx = threadIdx.x & 31;
    const int ty = threadIdx.x >> 5;
    const int c0 = bx * 64, r0 = by * 64;
#pragma unroll
    for (int i = 0; i < 8; ++i) {
        int r = ty + i * 8;
        float2 v = *(const float2*)(in + (size_t)(r0 + r) * C + c0 + tx * 2);
        tile[r][tx * 2] = v.x;
        tile[r][tx * 2 + 1] = v.y;
    }
    __syncthreads();
#pragma unroll
    for (int i = 0; i < 8; ++i) {
        int c = ty + i * 8;
        short2 o;
        o.x = f2bs(tile[tx * 2][c]);
        o.y = f2bs(tile[tx * 2 + 1][c]);
        *(short2*)(out + (size_t)(c0 + c) * R + r0 + tx * 2) = o;
    }
}

// ---------- layernorm fp32 row -> bf16 row, plus bf16 copy of x ----------
__global__ __launch_bounds__(256) void ln_kernel(const float* __restrict__ x,
                                                 const float* __restrict__ sc,
                                                 const float* __restrict__ sh,
                                                 short* __restrict__ out,
                                                 short* __restrict__ xb) {
    const int D = 2048;
    const int row = blockIdx.x;
    const int tid = threadIdx.x;
    __shared__ float red[4];
    const float4* xr = (const float4*)(x + (size_t)row * D);
    float4 v0 = xr[tid];
    float4 v1 = xr[tid + 256];
    float vals0[4] = {v0.x, v0.y, v0.z, v0.w};
    float vals1[4] = {v1.x, v1.y, v1.z, v1.w};

    float s = vals0[0] + vals0[1] + vals0[2] + vals0[3] + vals1[0] + vals1[1] + vals1[2] + vals1[3];
#pragma unroll
    for (int off = 32; off; off >>= 1) s += __shfl_xor(s, off);
    if ((tid & 63) == 0) red[tid >> 6] = s;
    __syncthreads();
    float mean = (red[0] + red[1] + red[2] + red[3]) * (1.0f / 2048.0f);
    __syncthreads();

    float q = 0.0f;
#pragma unroll
    for (int j = 0; j < 4; ++j) {
        float t0 = vals0[j] - mean;
        float t1 = vals1[j] - mean;
        q += t0 * t0 + t1 * t1;
    }
#pragma unroll
    for (int off = 32; off; off >>= 1) q += __shfl_xor(q, off);
    if ((tid & 63) == 0) red[tid >> 6] = q;
    __syncthreads();
    float var = (red[0] + red[1] + red[2] + red[3]) * (1.0f / 2048.0f);
    float inv = rsqrtf(var + 1e-5f);

    const int c0 = tid * 4;
    const int c1 = (tid + 256) * 4;
    short4v o0, o1, b0, b1;
#pragma unroll
    for (int j = 0; j < 4; ++j) {
        o0[j] = f2bs(sc[c0 + j] * ((vals0[j] - mean) * inv) + sh[c0 + j]);
        o1[j] = f2bs(sc[c1 + j] * ((vals1[j] - mean) * inv) + sh[c1 + j]);
        b0[j] = f2bs(vals0[j]);
        b1[j] = f2bs(vals1[j]);
    }
    *(short4v*)(out + (size_t)row * D + c0) = o0;
    *(short4v*)(out + (size_t)row * D + c1) = o1;
    *(short4v*)(xb + (size_t)row * D + c0) = b0;
    *(short4v*)(xb + (size_t)row * D + c1) = b1;
}

// ---------- layernorm bf16 row (D=2048) -> bf16 row ----------
__global__ __launch_bounds__(256) void ln_bf16_kernel(const short* __restrict__ x,
                                                      const float* __restrict__ sc,
                                                      const float* __restrict__ sh,
                                                      short* __restrict__ out) {
    const int D = 2048;
    const int row = blockIdx.x;
    const int tid = threadIdx.x;
    __shared__ float red[4];
    bf16x8 v = *(const bf16x8*)(x + (size_t)row * D + tid * 8);
    float vals[8];
#pragma unroll
    for (int j = 0; j < 8; ++j) vals[j] = bs2f(v[j]);

    float s = 0.f;
#pragma unroll
    for (int j = 0; j < 8; ++j) s += vals[j];
#pragma unroll
    for (int off = 32; off; off >>= 1) s += __shfl_xor(s, off);
    if ((tid & 63) == 0) red[tid >> 6] = s;
    __syncthreads();
    float mean = (red[0] + red[1] + red[2] + red[3]) * (1.0f / 2048.0f);
    __syncthreads();

    float q = 0.0f;
#pragma unroll
    for (int j = 0; j < 8; ++j) {
        float t = vals[j] - mean;
        q += t * t;
    }
#pragma unroll
    for (int off = 32; off; off >>= 1) q += __shfl_xor(q, off);
    if ((tid & 63) == 0) red[tid >> 6] = q;
    __syncthreads();
    float var = (red[0] + red[1] + red[2] + red[3]) * (1.0f / 2048.0f);
    float inv = rsqrtf(var + 1e-5f);

    const int c0 = tid * 8;
    bf16x8 o;
#pragma unroll
    for (int j = 0; j < 8; ++j)
        o[j] = f2bs(sc[c0 + j] * ((vals[j] - mean) * inv) + sh[c0 + j]);
    *(bf16x8*)(out + (size_t)row * D + c0) = o;
}

// ---------- gemm3b: 256x128, BK=32, 3-deep, 72KB LDS -> 2 blocks/CU --------
// 128B super-rows (M-row pair), 3-bit slot XOR: conflict-free.
// EPI 0: bf16   2: bf16 gelu(acc+bias)
template <int EPI>
__global__ __launch_bounds__(512, 4) void gemm3b(const short* __restrict__ A,
                                                 const short* __restrict__ Bt,
                                                 int M, int N, int K,
                                                 void* __restrict__ Cout,
                                                 const float* __restrict__ bias,
                                                 const float* __restrict__ res,
                                                 float gconst) {
    extern __shared__ __align__(16) short lds[];  // 3 * 12288 shorts = 72KB
    const int tid = threadIdx.x;
    const int lane = tid & 63;
    const int wid = tid >> 6;
    const int wm = wid >> 1, wn = wid & 1;
    const int l15 = lane & 15, grp = lane >> 4;

    const int gx = gridDim.x;
    int flat = (int)blockIdx.y * gx + (int)blockIdx.x;
    const int cpx = (gx * (int)gridDim.y) >> 3;
    flat = (flat & 7) * cpx + (flat >> 3);
    const int bx = flat % gx, by = flat / gx;
    const long m0 = (long)by * 256, n0 = (long)bx * 128;

    f32x4 zero = {0.f, 0.f, 0.f, 0.f};
    f32x4 acc[4][4];
#pragma unroll
    for (int i = 0; i < 4; i++)
#pragma unroll
        for (int j = 0; j < 4; j++) acc[i][j] = zero;

    auto STAGE = [&](int t, int b) {
        short* bufA = lds + b * 12288;
        short* bufB = bufA + 8192;
        const long k0 = (long)t << 5;
#pragma unroll
        for (int j = 0; j < 2; ++j) {
            int c = tid + j * 512;
            int sr = c >> 3, ps = c & 7;
            int ls = ps ^ (sr & 7);
            int row = sr * 2 + (ls >> 2), kc = ls & 3;
            gload_lds16(A + (size_t)(m0 + row) * K + k0 + kc * 8, bufA + (size_t)c * 8);
        }
        {
            int c = tid;
            int sr = c >> 3, ps = c & 7;
            int ls = ps ^ (sr & 7);
            int row = sr * 2 + (ls >> 2), kc = ls & 3;
            gload_lds16(Bt + (size_t)(n0 + row) * K + k0 + kc * 8, bufB + (size_t)c * 8);
        }
    };

    const int nt = K >> 5;
    STAGE(0, 0);
    STAGE(1, 1);
    int cur = 0, nx2 = 2;

    for (int t = 0; t < nt; ++t) {
        if (t + 2 < nt) {
            STAGE(t + 2, nx2);
            vmw<6>();
        } else if (t + 1 < nt) {
            vmw<3>();
        } else {
            vmw<0>();
        }
        __builtin_amdgcn_s_barrier();
        __builtin_amdgcn_sched_barrier(0);

        const short* bufA = lds + cur * 12288;
        const short* bufB = bufA + 8192;
        bf16x8 af[4], bfr[4];
#pragma unroll
        for (int m = 0; m < 4; ++m) {
            int row = wm * 64 + m * 16 + l15;
            int sr = row >> 1;
            int ps = ((row & 1) * 4 + grp) ^ (sr & 7);
            af[m] = *(const bf16x8*)(bufA + sr * 64 + ps * 8);
        }
#pragma unroll
        for (int n = 0; n < 4; ++n) {
            int row = wn * 64 + n * 16 + l15;
            int sr = row >> 1;
            int ps = ((row & 1) * 4 + grp) ^ (sr & 7);
            bfr[n] = *(const bf16x8*)(bufB + sr * 64 + ps * 8);
        }
        __builtin_amdgcn_s_setprio(1);
#pragma unroll
        for (int m = 0; m < 4; ++m)
#pragma unroll
            for (int n = 0; n < 4; ++n)
                acc[m][n] = MFMA16x32(af[m], bfr[n], acc[m][n]);
        __builtin_amdgcn_s_setprio(0);
        asm volatile("s_waitcnt lgkmcnt(0)" ::: "memory");
        __builtin_amdgcn_s_barrier();
        __builtin_amdgcn_sched_barrier(0);
        cur = (cur == 2) ? 0 : cur + 1;
        nx2 = (nx2 == 2) ? 0 : nx2 + 1;
    }

#pragma unroll
    for (int m = 0; m < 4; m++) {
        long gr = m0 + wm * 64 + m * 16 + grp * 4;
#pragma unroll
        for (int n = 0; n < 4; n++) {
            long gcol = n0 + wn * 64 + n * 16 + l15;
#pragma unroll
            for (int r = 0; r < 4; r++) {
                float vv = acc[m][n][r];
                long idx = (gr + r) * N + gcol;
                if constexpr (EPI == 0) {
                    ((short*)Cout)[idx] = f2bs(vv);
                } else {
                    float t2 = vv + bias[gcol];
                    float g = 0.5f * t2 * (1.0f + gconst * (t2 + 0.044715f * t2 * t2 * t2));
                    ((short*)Cout)[idx] = f2bs(g);
                }
            }
        }
    }
}

// ---------- gemm2c: 128x128, BK=64, 256 thr, 2-deep dbuf, 64KB -> 2 blk/CU --
// EPI 4: f32=acc+bias+bf16res   5: bf16=acc+bias+bf16res
template <int EPI>
__global__ __launch_bounds__(256, 2) void gemm2c(const short* __restrict__ A,
                                                 const short* __restrict__ Bt,
                                                 int M, int N, int K,
                                                 void* __restrict__ Cout,
                                                 const float* __restrict__ bias,
                                                 const float* __restrict__ res,
                                                 float gconst) {
    extern __shared__ __align__(16) short lds[];  // 2 * 16384 shorts = 64KB
    const int tid = threadIdx.x;
    const int lane = tid & 63;
    const int wid = tid >> 6;
    const int wm = wid >> 1, wn = wid & 1;
    const int l15 = lane & 15, grp = lane >> 4;

    const int gx = gridDim.x;
    int flat = (int)blockIdx.y * gx + (int)blockIdx.x;
    const int cpx = (gx * (int)gridDim.y) >> 3;
    flat = (flat & 7) * cpx + (flat >> 3);
    const int bx = flat % gx, by = flat / gx;
    const long m0 = (long)by * 128, n0 = (long)bx * 128;

    f32x4 zero = {0.f, 0.f, 0.f, 0.f};
    f32x4 acc[4][4];
#pragma unroll
    for (int i = 0; i < 4; i++)
#pragma unroll
        for (int j = 0; j < 4; j++) acc[i][j] = zero;

    auto STAGE = [&](int t, int b) {
        short* bufA = lds + b * 16384;
        short* bufB = bufA + 8192;
        const long k0 = (long)t << 6;
#pragma unroll
        for (int j = 0; j < 4; ++j) {
            int c = tid + j * 256;
            int row = c >> 3, sl = (c & 7) ^ (row & 7);
            gload_lds16(A + (size_t)(m0 + row) * K + k0 + sl * 8, bufA + (size_t)c * 8);
        }
#pragma unroll
        for (int j = 0; j < 4; ++j) {
            int c = tid + j * 256;
            int row = c >> 3, sl = (c & 7) ^ (row & 7);
            gload_lds16(Bt + (size_t)(n0 + row) * K + k0 + sl * 8, bufB + (size_t)c * 8);
        }
    };

    const int nt = K >> 6;
    STAGE(0, 0);
    STAGE(1, 1);

    for (int t = 0; t < nt; ++t) {
        if (t + 1 < nt) { vmw<8>(); } else { vmw<0>(); }
        __builtin_amdgcn_s_barrier();
        __builtin_amdgcn_sched_barrier(0);

        const short* bufA = lds + (t & 1) * 16384;
        const short* bufB = bufA + 8192;
        bf16x8 af[2][4], bfr[2][4];
#pragma unroll
        for (int kk = 0; kk < 2; ++kk) {
#pragma unroll
            for (int m = 0; m < 4; ++m) {
                int row = wm * 64 + m * 16 + l15;
                af[kk][m] = *(const bf16x8*)(bufA + row * 64 + (((kk * 4 + grp) ^ (row & 7)) * 8));
            }
#pragma unroll
            for (int n = 0; n < 4; ++n) {
                int row = wn * 64 + n * 16 + l15;
                bfr[kk][n] = *(const bf16x8*)(bufB + row * 64 + (((kk * 4 + grp) ^ (row & 7)) * 8));
            }
        }
        __builtin_amdgcn_s_setprio(1);
#pragma unroll
        for (int kk = 0; kk < 2; ++kk)
#pragma unroll
            for (int m = 0; m < 4; ++m)
#pragma unroll
                for (int n = 0; n < 4; ++n)
                    acc[m][n] = MFMA16x32(af[kk][m], bfr[kk][n], acc[m][n]);
        __builtin_amdgcn_s_setprio(0);
        asm volatile("s_waitcnt lgkmcnt(0)" ::: "memory");
        __builtin_amdgcn_s_barrier();
        __builtin_amdgcn_sched_barrier(0);
        if (t + 2 < nt) STAGE(t + 2, t & 1);
    }

#pragma unroll
    for (int m = 0; m < 4; m++) {
        long gr = m0 + wm * 64 + m * 16 + grp * 4;
#pragma unroll
        for (int n = 0; n < 4; n++) {
            long gcol = n0 + wn * 64 + n * 16 + l15;
#pragma unroll
            for (int r = 0; r < 4; r++) {
                float vv = acc[m][n][r];
                long idx = (gr + r) * N + gcol;
                if constexpr (EPI == 5) {
                    ((short*)Cout)[idx] = f2bs(vv + bias[gcol] + bs2f(((const short*)res)[idx]));
                } else {  // EPI == 4
                    ((float*)Cout)[idx] = vv + bias[gcol] + bs2f(((const short*)res)[idx]);
                }
            }
        }
    }
}

// ---------- reshape: qkv V-cols -> Vt[32][128][2048] (transposed) ----------
__global__ __launch_bounds__(256) void reshape_v_kernel(const short* __restrict__ qkv,
                                                        short* __restrict__ Vt) {
    __shared__ short tile[32][33];
    const int bid = blockIdx.x;
    const int dt = bid & 3, st = (bid >> 2) & 63, bh = bid >> 8;
    const int b = bh >> 4, h = bh & 15;
    const int s0 = st * 32, d0 = dt * 32;
    const int tx = threadIdx.x & 31, ty = threadIdx.x >> 5;
#pragma unroll
    for (int i = 0; i < 4; ++i) {
        int s = ty + i * 8;
        tile[s][tx] = qkv[(size_t)(b * 2048 + s0 + s) * 6144 + 4096 + h * 128 + d0 + tx];
    }
    __syncthreads();
#pragma unroll
    for (int i = 0; i < 4; ++i) {
        int d = ty + i * 8;
        Vt[((size_t)bh * 128 + d0 + d) * 2048 + s0 + tx] = tile[tx][d];
    }
}

// ---------- causal flash attention, paired q-tiles + double-buffered K/V ----
__global__ __launch_bounds__(256) void flash3_kernel(const short* __restrict__ qp,  // qkv, ld 6144
                                                     const short* __restrict__ Vt,
                                                     short* __restrict__ ctx) {
    const int S = 2048, D = 2048, HD = 128, LD = 6144;
    __shared__ __align__(16) short Ks[2][64 * 128];
    __shared__ __align__(16) short Vs[2][64 * 128];
    __shared__ __align__(16) short Ps[4][16 * 64];
    const int tid = threadIdx.x;
    const int lane = tid & 63, wid = tid >> 6;
    const int l15 = lane & 15, grp = lane >> 4;

    int bid = (int)blockIdx.x;
    bid = (bid & 7) * 64 + (bid >> 3);
    const int p = bid & 15, bh = bid >> 4;
    const int b = bh >> 4, h = bh & 15;
    const int qtH = 31 - p;
    const int nH = qtH + 1;
    const float scale = 0.08838834764831845f;
    const float NEGINF = -__builtin_inff();

    const short* Kbase = qp + (size_t)b * S * LD + 2048 + (size_t)h * HD;
    const short* Vbase = Vt + (size_t)bh * 128 * S;
    short* Psw = &Ps[wid][0];

    f32x4 zero = {0.f, 0.f, 0.f, 0.f};
    bf16x8 aq[4];
    float m_[4], l_[4];
    f32x4 o[8];

    int qt = qtH;
    int qw = qt * 64 + wid * 16;
    {
        const short* qrow = qp + (size_t)(b * S + qw + l15) * LD + h * HD;
#pragma unroll
        for (int kc = 0; kc < 4; kc++) aq[kc] = *(const bf16x8*)(qrow + kc * 32 + grp * 8);
    }
#pragma unroll
    for (int r = 0; r < 4; r++) { m_[r] = NEGINF; l_[r] = 0.f; }
#pragma unroll
    for (int n = 0; n < 8; n++) o[n] = zero;

#pragma unroll
    for (int j = 0; j < 4; ++j) {
        int c = tid + j * 256;
        int r = c >> 4, sl = c & 15;
        gload_lds16(Kbase + (size_t)r * LD + ((sl ^ (r & 7)) * 8),
                    Ks[0] + (size_t)(wid * 64 + j * 256) * 8);
    }
#pragma unroll
    for (int j = 0; j < 4; ++j) {
        int c = tid + j * 256;
        int d = c >> 3, sl = c & 7;
        gload_lds16(Vbase + (size_t)d * S + ((sl ^ (d & 7)) * 8),
                    Vs[0] + (size_t)(wid * 64 + j * 256) * 8);
    }
    __syncthreads();

    int cur = 0;
    for (int i = 0; i < 33; ++i) {
        const int kt = (i < nH) ? i : (i - nH);
        const bool lastT = (kt == qt);

        if (i + 1 < 33) {
            const int ktn = (i + 1 < nH) ? (i + 1) : (i + 1 - nH);
            const long kn0 = (long)ktn * 64;
            const short* Kg = Kbase + (size_t)kn0 * LD;
            const short* Vg = Vbase + kn0;
            short* kd = Ks[cur ^ 1];
            short* vd = Vs[cur ^ 1];
#pragma unroll
            for (int j = 0; j < 4; ++j) {
                int c = tid + j * 256;
                int r = c >> 4, sl = c & 15;
                gload_lds16(Kg + (size_t)r * LD + ((sl ^ (r & 7)) * 8),
                            kd + (size_t)(wid * 64 + j * 256) * 8);
            }
#pragma unroll
            for (int j = 0; j < 4; ++j) {
                int c = tid + j * 256;
                int d = c >> 3, sl = c & 7;
                gload_lds16(Vg + (size_t)d * S + ((sl ^ (d & 7)) * 8),
                            vd + (size_t)(wid * 64 + j * 256) * 8);
            }
        }

        const short* Kc = Ks[cur];
        const short* Vc = Vs[cur];

        f32x4 s[4] = {zero, zero, zero, zero};
        __builtin_amdgcn_s_setprio(1);
#pragma unroll
        for (int n = 0; n < 4; ++n) {
            int r = n * 16 + l15;
#pragma unroll
            for (int kc = 0; kc < 4; ++kc) {
                bf16x8 kb = *(const bf16x8*)(Kc + r * 128 + (((kc * 4 + grp) ^ (r & 7)) * 8));
                s[n] = MFMA16x32(aq[kc], kb, s[n]);
            }
        }
        __builtin_amdgcn_s_setprio(0);

        float al[4];
#pragma unroll
        for (int r = 0; r < 4; ++r) {
            float v[4];
#pragma unroll
            for (int n = 0; n < 4; ++n) v[n] = s[n][r] * scale;
            if (lastT) {
                int qrel = wid * 16 + grp * 4 + r;
#pragma unroll
                for (int n = 0; n < 4; ++n)
                    if (n * 16 + l15 > qrel) v[n] = NEGINF;
            }
            float mx = fmaxf(fmaxf(v[0], v[1]), fmaxf(v[2], v[3]));
            mx = fmaxf(mx, __shfl_xor(mx, 1));
            mx = fmaxf(mx, __shfl_xor(mx, 2));
            mx = fmaxf(mx, __shfl_xor(mx, 4));
            mx = fmaxf(mx, __shfl_xor(mx, 8));
            float mn = fmaxf(m_[r], mx);
            float sc_ = __expf(m_[r] - mn);
            float rs = 0.f;
            int q = grp * 4 + r;
#pragma unroll
            for (int n = 0; n < 4; ++n) {
                v[n] = __expf(v[n] - mn);
                rs += v[n];
                Psw[q * 64 + (((n * 2 + (l15 >> 3)) ^ (q & 7)) * 8) + (l15 & 7)] = f2bs(v[n]);
            }
            rs += __shfl_xor(rs, 1);
            rs += __shfl_xor(rs, 2);
            rs += __shfl_xor(rs, 4);
            rs += __shfl_xor(rs, 8);
            l_[r] = l_[r] * sc_ + rs;
            m_[r] = mn;
            al[r] = sc_;
        }
#pragma unroll
        for (int n = 0; n < 8; n++) {
            f32x4 t = o[n];
            t[0] *= al[0]; t[1] *= al[1]; t[2] *= al[2]; t[3] *= al[3];
            o[n] = t;
        }

        bf16x8 pa[2];
#pragma unroll
        for (int kc = 0; kc < 2; ++kc)
            pa[kc] = *(const bf16x8*)(Psw + l15 * 64 + (((kc * 4 + grp) ^ (l15 & 7)) * 8));
        __builtin_amdgcn_s_setprio(1);
#pragma unroll
        for (int n = 0; n < 8; ++n) {
            int d = n * 16 + l15;
#pragma unroll
            for (int kc = 0; kc < 2; ++kc) {
                bf16x8 vb = *(const bf16x8*)(Vc + d * 64 + (((kc * 4 + grp) ^ (d & 7)) * 8));
                o[n] = MFMA16x32(pa[kc], vb, o[n]);
            }
        }
        __builtin_amdgcn_s_setprio(0);

        if (lastT) {
            float inv[4];
#pragma unroll
            for (int r = 0; r < 4; ++r) inv[r] = 1.0f / l_[r];
            short* cb_ = ctx + (size_t)(b * S + qw + grp * 4) * D + h * HD + l15;
#pragma unroll
            for (int n = 0; n < 8; ++n)
#pragma unroll
                for (int r = 0; r < 4; ++r)
                    cb_[(size_t)r * D + n * 16] = f2bs(o[n][r] * inv[r]);
            if (i < 32) {
                qt = 31 - qtH;
                qw = qt * 64 + wid * 16;
                const short* qrow = qp + (size_t)(b * S + qw + l15) * LD + h * HD;
#pragma unroll
                for (int kc = 0; kc < 4; kc++) aq[kc] = *(const bf16x8*)(qrow + kc * 32 + grp * 8);
#pragma unroll
                for (int r = 0; r < 4; r++) { m_[r] = NEGINF; l_[r] = 0.f; }
#pragma unroll
                for (int n = 0; n < 8; n++) o[n] = zero;
            }
        }
        __syncthreads();
        cur ^= 1;
    }
}

// ---------------------------------------------------------------------------
extern "C" void kernel_launch(void* const* d_in, const int* in_sizes, int n_in,
                              void* d_out, int out_size, void* d_ws, size_t ws_size,
                              hipStream_t stream) {
    const float* x    = (const float*)d_in[0];
    const float* wq   = (const float*)d_in[1];
    const float* wk   = (const float*)d_in[2];
    const float* wv   = (const float*)d_in[3];
    const float* wo   = (const float*)d_in[4];
    const float* bo   = (const float*)d_in[5];
    const float* w1   = (const float*)d_in[6];
    const float* b1   = (const float*)d_in[7];
    const float* w2   = (const float*)d_in[8];
    const float* b2   = (const float*)d_in[9];
    const float* lnsc = (const float*)d_in[10];
    const float* lnsh = (const float*)d_in[11];

    const int B = 2, S = 2048, D = 2048;
    const int M = B * S;  // 4096
    const int LDS_3B = 3 * 12288 * 2;   // 73728 (gemm3b)
    const int LDS_2C = 2 * 16384 * 2;   // 65536 (gemm2c)

    char* p = (char*)d_ws;
    short* wqkvT = (short*)p; p += (size_t)3 * D * D * 2;
    short* woT   = (short*)p; p += (size_t)D * D * 2;
    short* w1T   = (short*)p; p += (size_t)4 * D * D * 2;
    short* w2T   = (short*)p; p += (size_t)4 * D * D * 2;
    short* lnb   = (short*)p; p += (size_t)M * D * 2;
    short* qkvb  = (short*)p;
    short* h1    = qkvb;                                    // reuse qkv+ctx span
    p += (size_t)M * 3 * D * 2;
    short* ctxb  = (short*)p; p += (size_t)M * D * 2;
    short* x2    = (short*)p; p += (size_t)M * D * 2;       // bf16 residual (attn out)
    short* xb16  = (short*)p; p += (size_t)M * D * 2;       // bf16 copy of x

    short* Vt = x2;             // overlays x2 (proj writes x2 only after flash)

    const float gconst = tanhf(sqrtf(2.0f / 3.14159265358979323846f));

    hipFuncSetAttribute((const void*)&gemm3b<0>, hipFuncAttributeMaxDynamicSharedMemorySize, LDS_3B);
    hipFuncSetAttribute((const void*)&gemm3b<2>, hipFuncAttributeMaxDynamicSharedMemorySize, LDS_3B);
    hipFuncSetAttribute((const void*)&gemm2c<5>, hipFuncAttributeMaxDynamicSharedMemorySize, LDS_2C);
    hipFuncSetAttribute((const void*)&gemm2c<4>, hipFuncAttributeMaxDynamicSharedMemorySize, LDS_2C);

    dim3 blk(256);
    transpose_all_kernel<<<dim3(12288), blk, 0, stream>>>(
        wq, wk, wv, wo, w1, w2, wqkvT, woT, w1T, w2T);

    ln_kernel<<<dim3(M), blk, 0, stream>>>(x, lnsc, lnsh, lnb, xb16);
    // qkv: gemm3b -> grid 48x16 = 768 blocks
    gemm3b<0><<<dim3(3 * D / 128, M / 256), dim3(512), LDS_3B, stream>>>(
        lnb, wqkvT, M, 3 * D, D, qkvb, nullptr, nullptr, 0.f);

    reshape_v_kernel<<<dim3(8192), blk, 0, stream>>>(qkvb, Vt);

    flash3_kernel<<<dim3(512), blk, 0, stream>>>(qkvb, Vt, ctxb);

    // proj: gemm2c EPI5 (bf16 out = acc + bo + bf16 x) -> grid 16x32 = 512
    gemm2c<5><<<dim3(D / 128, M / 128), blk, LDS_2C, stream>>>(
        ctxb, woT, M, D, D, x2, bo, (const float*)xb16, 0.f);
    ln_bf16_kernel<<<dim3(M), blk, 0, stream>>>(x2, lnsc, lnsh, lnb);
    // ffn1: gemm3b -> grid 64x16 = 1024 blocks
    gemm3b<2><<<dim3(4 * D / 128, M / 256), dim3(512), LDS_3B, stream>>>(
        lnb, w1T, M, 4 * D, D, h1, b1, nullptr, gconst);
    // ffn2: gemm2c EPI4 (f32 out = acc + b2 + bf16 x2) -> grid 16x32 = 512
    gemm2c<4><<<dim3(D / 128, M / 128), blk, LDS_2C, stream>>>(
        h1, w2T, M, D, 4 * D, (float*)d_out, b2, (const float*)x2, 0.f);
}